// Round 13
// baseline (130.767 us; speedup 1.0000x reference)
//
#include <hip/hip_runtime.h>
#include <math.h>

#define NN 100000
#define F_IN 128
#define F_OUT 40
#define BSHIFT 9        // 512 nodes per bucket
#define BSIZE (1 << BSHIFT)
#define NBUCK ((NN + BSIZE - 1) >> BSHIFT)   // 196
#define SCAP 12288      // staged slots per bucket
#define CAP 16384       // padded adj slots per bucket (pad9+quad-eq, mean ~13.1k)
#define EPB_C 16384
// split feature layout: A = cols 0..31 (64 B rows), B = cols 32..39 (16 B rows)
#define OFFB  ((unsigned)((NN + 1) * 64))        // start of B block
#define ADUM  ((unsigned)(NN * 64))              // A dummy row (zeros)
#define XSBYTES ((size_t)8000128)                // (N+1)*80 rounded up

typedef short bf16x8 __attribute__((ext_vector_type(8)));
typedef float f32x4 __attribute__((ext_vector_type(4)));
typedef _Float16 h2 __attribute__((ext_vector_type(2)));

union U4H { uint4 u; h2 h[4]; };

__device__ __forceinline__ short f2bf(float f) {
    union { float f; unsigned u; } uf; uf.f = f;
    unsigned r = uf.u + 0x7FFF + ((uf.u >> 16) & 1);   // RNE
    return (short)(r >> 16);
}

__device__ __forceinline__ unsigned pack16(float x, float y) {
    union { _Float16 h; unsigned short s; } a, b;
    a.h = (_Float16)x; b.h = (_Float16)y;
    return (unsigned)a.s | ((unsigned)b.s << 16);
}

__device__ __forceinline__ h2 shfl_h2(h2 v, int src) {
    int x = __builtin_bit_cast(int, v);
    x = __shfl(x, src);
    return __builtin_bit_cast(h2, x);
}

// ---- setup: bcursor[bk]=bk*SCAP; zero dummy rows (A + B) in both buffers ----
__global__ void setup_kernel(int* __restrict__ bcursor, char* xs1, char* xs2) {
    int t = threadIdx.x;
    if (t < NBUCK) bcursor[t] = t * SCAP;
    if (t < 16)      *(unsigned*)(xs1 + ADUM + t * 4) = 0u;
    else if (t < 20) *(unsigned*)(xs1 + OFFB + (size_t)NN * 16 + (t - 16) * 4) = 0u;
    else if (t < 36) *(unsigned*)(xs2 + ADUM + (t - 20) * 4) = 0u;
    else if (t < 40) *(unsigned*)(xs2 + OFFB + (size_t)NN * 16 + (t - 36) * 4) = 0u;
}

// ---- partition edges into fixed per-bucket staged regions; packs (c_local<<17)|row ----
__global__ void part_kernel(const int* __restrict__ row, const int* __restrict__ col,
                            int* __restrict__ bcursor, int* __restrict__ staged, int E) {
    __shared__ int h[NBUCK];
    __shared__ int cur[NBUCK];
    for (int i = threadIdx.x; i < NBUCK; i += blockDim.x) h[i] = 0;
    __syncthreads();
    int e0 = blockIdx.x * EPB_C;
    int e1 = min(e0 + EPB_C, E);
    for (int e = e0 + threadIdx.x; e < e1; e += blockDim.x)
        atomicAdd(&h[col[e] >> BSHIFT], 1);
    __syncthreads();
    for (int i = threadIdx.x; i < NBUCK; i += blockDim.x)
        cur[i] = h[i] ? atomicAdd(&bcursor[i], h[i]) : 0;
    __syncthreads();
    for (int e = e0 + threadIdx.x; e < e1; e += blockDim.x) {
        int c = col[e];
        int pos = atomicAdd(&cur[c >> BSHIFT], 1);
        staged[pos] = ((c & (BSIZE - 1)) << 17) | row[e];
    }
}

// ---- padded per-bucket CSR. Segment: [self, edges..., NN pads], length pad9(deg+1),
// quad-equalized (nodes 4i..4i+3 share L). Wave-shfl scan. ----
__global__ void __launch_bounds__(512) build_kernel(const int* __restrict__ staged,
                                                    const int* __restrict__ bcursor,
                                                    int* __restrict__ adj,
                                                    int* __restrict__ offs,
                                                    float* __restrict__ dinv, int N) {
    __shared__ int hist[BSIZE];
    __shared__ int cur[BSIZE];
    __shared__ int wsum[8];
    int bk = blockIdx.x;
    int node0 = bk << BSHIFT;
    int sbase = bk * SCAP;
    int send = bcursor[bk];
    int gbase = bk * CAP;
    int i = threadIdx.x;
    hist[i] = 0;
    __syncthreads();
    for (int e = sbase + i; e < send; e += 512)
        atomicAdd(&hist[staged[e] >> 17], 1);
    __syncthreads();
    int v = hist[i];
    int Lp = ((v + 9) / 9) * 9;            // pad9(deg+1)
    int L1 = max(Lp, __shfl_xor(Lp, 1));
    int LL = max(L1, __shfl_xor(L1, 2));   // quad-equalized
    int lane = i & 63, w = i >> 6;
    int x = LL;
#pragma unroll
    for (int d = 1; d < 64; d <<= 1) {
        int y = __shfl_up(x, d, 64);
        if (lane >= d) x += y;
    }
    if (lane == 63) wsum[w] = x;
    __syncthreads();
    int wpre = 0;
    for (int k = 0; k < w; ++k) wpre += wsum[k];
    int excl = wpre + x - LL;
    int n = node0 + i;
    if (n < N) {
        offs[n] = gbase + excl;
        dinv[n] = rsqrtf((float)v + 1.0f);
        adj[gbase + excl] = n;                        // self edge first
        for (int p = excl + 1 + v; p < excl + LL; ++p)
            adj[gbase + p] = NN;                      // pads -> dummy row
    }
    cur[i] = excl + 1;
    __syncthreads();
    for (int e = sbase + i; e < send; e += 512) {
        int sv = staged[e];
        int pos = atomicAdd(&cur[sv >> 17], 1);
        adj[gbase + pos] = sv & 0x1FFFF;
    }
}

// ---- MFMA gemm: xs1[n] = (x[n] . W) * dinv[n]; fp16, split A/B layout ----
__global__ void __launch_bounds__(256) gemm_kernel(const float* __restrict__ x,
                                                   const float* __restrict__ w,
                                                   const float* __restrict__ dinv,
                                                   char* __restrict__ xsb, int N) {
    __shared__ bf16x8 shB[3][4][64];
    int t = threadIdx.x;
    for (int idx = t; idx < 3 * 4 * 64; idx += 256) {
        int lane = idx & 63;
        int ks = (idx >> 6) & 3;
        int jt = idx >> 8;
        int j = 16 * jt + (lane & 15);
        int k0 = 32 * ks + 8 * (lane >> 4);
        bf16x8 v;
#pragma unroll
        for (int i = 0; i < 8; ++i)
            v[i] = (j < F_OUT) ? f2bf(w[(k0 + i) * F_OUT + j]) : (short)0;
        shB[jt][ks][lane] = v;
    }
    __syncthreads();
    int wave = t >> 6, lane = t & 63;
    int node0 = blockIdx.x * 64 + wave * 16;
    if (node0 >= N) return;

    const float* xrow = x + (size_t)(node0 + (lane & 15)) * F_IN + 8 * (lane >> 4);
    f32x4 acc0 = {0.f, 0.f, 0.f, 0.f};
    f32x4 acc1 = acc0, acc2 = acc0;
#pragma unroll
    for (int ks = 0; ks < 4; ++ks) {
        float4 lo = *(const float4*)(xrow + 32 * ks);
        float4 hi = *(const float4*)(xrow + 32 * ks + 4);
        bf16x8 a;
        a[0] = f2bf(lo.x); a[1] = f2bf(lo.y); a[2] = f2bf(lo.z); a[3] = f2bf(lo.w);
        a[4] = f2bf(hi.x); a[5] = f2bf(hi.y); a[6] = f2bf(hi.z); a[7] = f2bf(hi.w);
        acc0 = __builtin_amdgcn_mfma_f32_16x16x32_bf16(a, shB[0][ks][lane], acc0, 0, 0, 0);
        acc1 = __builtin_amdgcn_mfma_f32_16x16x32_bf16(a, shB[1][ks][lane], acc1, 0, 0, 0);
        acc2 = __builtin_amdgcn_mfma_f32_16x16x32_bf16(a, shB[2][ks][lane], acc2, 0, 0, 0);
    }
    int colj = lane & 15;
    int rbase = (lane >> 4) * 4;
#pragma unroll
    for (int r = 0; r < 4; ++r) {
        int node = node0 + rbase + r;
        float d = dinv[node];
        _Float16* dstA = (_Float16*)(xsb + (size_t)node * 64);
        dstA[colj]      = (_Float16)(acc0[r] * d);
        dstA[16 + colj] = (_Float16)(acc1[r] * d);
        if (colj < 8)
            ((_Float16*)(xsb + OFFB + (size_t)node * 16))[colj] = (_Float16)(acc2[r] * d);
    }
}

// ---- hop: wave = 4 nodes; lane = (node, sub 0..15). sub<15: edge slot s=sub/5,
// chunk q=sub%5 (q<4 -> A 16B chunk q, q==4 -> B 16B). lane 15: stride-0 dummy.
// Depth-3 software pipeline: 3 gathers + 3 adj loads in flight per slot group. ----
template <int HOP2>
__global__ void __launch_bounds__(256) hop_kernel(const int* __restrict__ offs,
                                                  const float* __restrict__ dinv,
                                                  const int* __restrict__ adj,
                                                  const char* __restrict__ src,
                                                  char* __restrict__ dst,
                                                  const float* __restrict__ bias,
                                                  float* __restrict__ out) {
    int t = threadIdx.x;
    int wave = t >> 6, lane = t & 63;
    int n0 = blockIdx.x * 16 + wave * 4;
    int node = lane >> 4;
    int sub = lane & 15;
    int n = n0 + node;
    int s = sub / 5;                 // 0..3 (3 only for sub==15)
    int q = sub - s * 5;             // 0..4
    bool padl = (sub == 15);
    unsigned strideB = padl ? 0u : (q == 4 ? 16u : 64u);
    unsigned cstB    = padl ? ADUM : (q == 4 ? OFFB : (unsigned)(q * 16));

    int obase = offs[n];
    int L = offs[n0 + 1] - offs[n0];      // quad-equal, multiple of 9
    int nj = L / 3;                       // slot-iterations, multiple of 3

    h2 A0 = {0.f, 0.f}, A1 = A0, A2 = A0, A3 = A0;
#define ACC4(g) do { A0 += g.h[0]; A1 += g.h[1]; A2 += g.h[2]; A3 += g.h[3]; } while (0)
#define LDG(r) (*(const uint4*)(src + (unsigned)(r) * strideB + cstB))

    int p = obase + s;
    int aA = adj[p];     U4H g0; g0.u = LDG(aA);
    int aB = adj[p + 3]; U4H g1; g1.u = LDG(aB);
    int aC = adj[p + 6]; U4H g2; g2.u = LDG(aC);
    int steps = nj / 3 - 1;
    p += 9;
    for (int tt = 0; tt < steps; ++tt, p += 9) {
        int nA = adj[p];     ACC4(g0); g0.u = LDG(nA);
        int nB = adj[p + 3]; ACC4(g1); g1.u = LDG(nB);
        int nC = adj[p + 6]; ACC4(g2); g2.u = LDG(nC);
    }
    ACC4(g0); ACC4(g1); ACC4(g2);
#undef ACC4
#undef LDG

    // reduce across the 3 edge slots: lanes sub, sub+5, sub+10 (mod 15) share q
    int nb = lane & 0x30;
    int i1 = nb | ((sub + 5) % 15);
    int i2 = nb | ((sub + 10) % 15);
    A0 = A0 + shfl_h2(A0, i1) + shfl_h2(A0, i2);
    A1 = A1 + shfl_h2(A1, i1) + shfl_h2(A1, i2);
    A2 = A2 + shfl_h2(A2, i1) + shfl_h2(A2, i2);
    A3 = A3 + shfl_h2(A3, i1) + shfl_h2(A3, i2);

    float f0 = (float)A0[0], f1 = (float)A0[1];
    float f2 = (float)A1[0], f3 = (float)A1[1];
    float f4 = (float)A2[0], f5 = (float)A2[1];
    float f6 = (float)A3[0], f7 = (float)A3[1];

    if (!HOP2) {
        if (sub < 5) {
            float d = dinv[n];
            float dd = d * d;
            uint4 wv;
            wv.x = pack16(f0 * dd, f1 * dd);
            wv.y = pack16(f2 * dd, f3 * dd);
            wv.z = pack16(f4 * dd, f5 * dd);
            wv.w = pack16(f6 * dd, f7 * dd);
            *(uint4*)(dst + (unsigned)n * strideB + cstB) = wv;
        }
    } else {
        float d = dinv[n];
        float4 b0 = ((const float4*)bias)[2 * q];
        float4 b1 = ((const float4*)bias)[2 * q + 1];
        float l0 = f0 * d + b0.x, l1 = f1 * d + b0.y;
        float l2 = f2 * d + b0.z, l3 = f3 * d + b0.w;
        float l4 = f4 * d + b1.x, l5 = f5 * d + b1.y;
        float l6 = f6 * d + b1.z, l7 = f7 * d + b1.w;
        float mp = fmaxf(fmaxf(fmaxf(l0, l1), fmaxf(l2, l3)),
                         fmaxf(fmaxf(l4, l5), fmaxf(l6, l7)));
        float m = mp;
#pragma unroll
        for (int dd = 1; dd <= 4; ++dd)
            m = fmaxf(m, __shfl(mp, nb | ((sub + dd) % 5)));
        const float R = 1.44269504089f;
        float sp = exp2f((l0 - m) * R) + exp2f((l1 - m) * R)
                 + exp2f((l2 - m) * R) + exp2f((l3 - m) * R)
                 + exp2f((l4 - m) * R) + exp2f((l5 - m) * R)
                 + exp2f((l6 - m) * R) + exp2f((l7 - m) * R);
        float sx = sp;
#pragma unroll
        for (int dd = 1; dd <= 4; ++dd)
            sx += __shfl(sp, nb | ((sub + dd) % 5));
        if (sub < 5) {
            float ls = m + 0.69314718056f * log2f(sx);
            float4 q0 = {l0 - ls, l1 - ls, l2 - ls, l3 - ls};
            float4 q1 = {l4 - ls, l5 - ls, l6 - ls, l7 - ls};
            float* op = out + (size_t)n * F_OUT + 8 * q;
            *(float4*)op = q0;
            *(float4*)(op + 4) = q1;
        }
    }
}

extern "C" void kernel_launch(void* const* d_in, const int* in_sizes, int n_in,
                              void* d_out, int out_size, void* d_ws, size_t ws_size,
                              hipStream_t stream) {
    const float* x    = (const float*)d_in[0];
    const int*   eidx = (const int*)d_in[1];
    const float* w    = (const float*)d_in[2];
    const float* bias = (const float*)d_in[3];
    float* out = (float*)d_out;

    const int E = in_sizes[1] / 2;
    const int N = NN;

    char* ws = (char*)d_ws;
    int*   bcursor = (int*)ws;   ws += 256 * 4;
    int*   offs    = (int*)ws;   ws += (size_t)N * 4;
    float* dinv    = (float*)ws; ws += (size_t)N * 4;
    int*   adj     = (int*)ws;   ws += (size_t)NBUCK * CAP * 4;   // 12.85 MB
    char*  xs1     = ws;         ws += XSBYTES;                   // 8.0 MB (A+B)
    char*  xs2     = ws;         ws += XSBYTES;
    int*   staged  = (int*)ws;                                    // 9.6 MB

    const int* row = eidx;
    const int* col = eidx + E;

    setup_kernel<<<1, 256, 0, stream>>>(bcursor, xs1, xs2);
    part_kernel<<<(E + EPB_C - 1) / EPB_C, 1024, 0, stream>>>(row, col, bcursor, staged, E);
    build_kernel<<<NBUCK, 512, 0, stream>>>(staged, bcursor, adj, offs, dinv, N);

    gemm_kernel<<<(N + 63) / 64, 256, 0, stream>>>(x, w, dinv, xs1, N);

    hop_kernel<0><<<N / 16, 256, 0, stream>>>(offs, dinv, adj, xs1, xs2, bias, out);
    hop_kernel<1><<<N / 16, 256, 0, stream>>>(offs, dinv, adj, xs2, nullptr, bias, out);
}

// Round 14
// 124.501 us; speedup vs baseline: 1.0503x; 1.0503x over previous
//
#include <hip/hip_runtime.h>
#include <math.h>

#define NN 100000
#define F_IN 128
#define F_OUT 40
#define BSHIFT 9        // 512 nodes per bucket
#define BSIZE (1 << BSHIFT)
#define NBUCK ((NN + BSIZE - 1) >> BSHIFT)   // 196
#define SCAP 12288      // staged slots per bucket
#define CAP 14336       // padded adj slots per bucket (pad3 + quad-eq)
#define EPB_C 4096      // edges per part block (391 blocks -> all CUs busy)
// split feature layout: A = cols 0..31 (64 B rows), B = cols 32..39 (16 B rows)
#define OFFB  ((unsigned)((NN + 1) * 64))        // start of B block
#define ADUM  ((unsigned)(NN * 64))              // A dummy row (zeros)
#define XSBYTES ((size_t)8000128)                // (N+1)*80 rounded up

typedef short bf16x8 __attribute__((ext_vector_type(8)));
typedef float f32x4 __attribute__((ext_vector_type(4)));
typedef _Float16 h2 __attribute__((ext_vector_type(2)));

union U4H { uint4 u; h2 h[4]; };

__device__ __forceinline__ short f2bf(float f) {
    union { float f; unsigned u; } uf; uf.f = f;
    unsigned r = uf.u + 0x7FFF + ((uf.u >> 16) & 1);   // RNE
    return (short)(r >> 16);
}

__device__ __forceinline__ unsigned pack16(float x, float y) {
    union { _Float16 h; unsigned short s; } a, b;
    a.h = (_Float16)x; b.h = (_Float16)y;
    return (unsigned)a.s | ((unsigned)b.s << 16);
}

__device__ __forceinline__ h2 shfl_h2(h2 v, int src) {
    int x = __builtin_bit_cast(int, v);
    x = __shfl(x, src);
    return __builtin_bit_cast(h2, x);
}

// ---- setup: bcursor[bk*16]=bk*SCAP (line-padded); zero dummy rows (A+B) both bufs ----
__global__ void setup_kernel(int* __restrict__ bcursor, char* xs1, char* xs2) {
    int t = threadIdx.x;
    if (t < NBUCK) bcursor[t * 16] = t * SCAP;
    if (t < 16)      *(unsigned*)(xs1 + ADUM + t * 4) = 0u;
    else if (t < 20) *(unsigned*)(xs1 + OFFB + (size_t)NN * 16 + (t - 16) * 4) = 0u;
    else if (t < 36) *(unsigned*)(xs2 + ADUM + (t - 20) * 4) = 0u;
    else if (t < 40) *(unsigned*)(xs2 + OFFB + (size_t)NN * 16 + (t - 36) * 4) = 0u;
}

// ---- partition edges into fixed per-bucket staged regions; packs (c_local<<17)|row.
// int4-vectorized both passes (E and block offsets are multiples of 4). ----
__global__ void __launch_bounds__(512) part_kernel(const int* __restrict__ row,
                                                   const int* __restrict__ col,
                                                   int* __restrict__ bcursor,
                                                   int* __restrict__ staged, int E) {
    __shared__ int h[NBUCK];
    __shared__ int cur[NBUCK];
    int t = threadIdx.x;
    for (int i = t; i < NBUCK; i += 512) h[i] = 0;
    __syncthreads();
    int e0 = blockIdx.x * EPB_C;
    int ne = min(EPB_C, E - e0);
    int nq = ne >> 2;
    const int4* c4 = (const int4*)(col + e0);
    const int4* r4 = (const int4*)(row + e0);
    for (int k = t; k < nq; k += 512) {
        int4 c = c4[k];
        atomicAdd(&h[c.x >> BSHIFT], 1);
        atomicAdd(&h[c.y >> BSHIFT], 1);
        atomicAdd(&h[c.z >> BSHIFT], 1);
        atomicAdd(&h[c.w >> BSHIFT], 1);
    }
    __syncthreads();
    for (int i = t; i < NBUCK; i += 512)
        cur[i] = h[i] ? atomicAdd(&bcursor[i * 16], h[i]) : 0;
    __syncthreads();
    for (int k = t; k < nq; k += 512) {
        int4 c = c4[k];
        int4 r = r4[k];
        int p;
        p = atomicAdd(&cur[c.x >> BSHIFT], 1); staged[p] = ((c.x & 511) << 17) | r.x;
        p = atomicAdd(&cur[c.y >> BSHIFT], 1); staged[p] = ((c.y & 511) << 17) | r.y;
        p = atomicAdd(&cur[c.z >> BSHIFT], 1); staged[p] = ((c.z & 511) << 17) | r.z;
        p = atomicAdd(&cur[c.w >> BSHIFT], 1); staged[p] = ((c.w & 511) << 17) | r.w;
    }
}

// ---- padded per-bucket CSR. Segment: [self, edges..., NN pads], length pad3(deg+1),
// quad-equalized (nodes 4i..4i+3 share L). int4 staged reads; wave-shfl scan. ----
__global__ void __launch_bounds__(512) build_kernel(const int* __restrict__ staged,
                                                    const int* __restrict__ bcursor,
                                                    int* __restrict__ adj,
                                                    int* __restrict__ offs,
                                                    float* __restrict__ dinv, int N) {
    __shared__ int hist[BSIZE];
    __shared__ int cur[BSIZE];
    __shared__ int wsum[8];
    int bk = blockIdx.x;
    int node0 = bk << BSHIFT;
    int sbase = bk * SCAP;
    int count = bcursor[bk * 16] - sbase;
    int gbase = bk * CAP;
    int i = threadIdx.x;
    hist[i] = 0;
    __syncthreads();
    int nq = count >> 2;
    const int4* st4 = (const int4*)(staged + sbase);
    for (int k = i; k < nq; k += 512) {
        int4 s = st4[k];
        atomicAdd(&hist[s.x >> 17], 1);
        atomicAdd(&hist[s.y >> 17], 1);
        atomicAdd(&hist[s.z >> 17], 1);
        atomicAdd(&hist[s.w >> 17], 1);
    }
    int tb = sbase + (nq << 2);
    if (i < (count & 3)) atomicAdd(&hist[staged[tb + i] >> 17], 1);
    __syncthreads();
    int v = hist[i];
    int Lp = ((v + 3) / 3) * 3;            // pad3(deg+1)
    int L1 = max(Lp, __shfl_xor(Lp, 1));
    int LL = max(L1, __shfl_xor(L1, 2));   // quad-equalized
    int lane = i & 63, w = i >> 6;
    int x = LL;
#pragma unroll
    for (int d = 1; d < 64; d <<= 1) {
        int y = __shfl_up(x, d, 64);
        if (lane >= d) x += y;
    }
    if (lane == 63) wsum[w] = x;
    __syncthreads();
    int wpre = 0;
    for (int k = 0; k < w; ++k) wpre += wsum[k];
    int excl = wpre + x - LL;
    int n = node0 + i;
    if (n < N) {
        offs[n] = gbase + excl;
        dinv[n] = rsqrtf((float)v + 1.0f);
        adj[gbase + excl] = n;                        // self edge first
        for (int p = excl + 1 + v; p < excl + LL; ++p)
            adj[gbase + p] = NN;                      // pads -> dummy row
    }
    cur[i] = excl + 1;
    __syncthreads();
    for (int k = i; k < nq; k += 512) {
        int4 s = st4[k];
        int p;
        p = atomicAdd(&cur[s.x >> 17], 1); adj[gbase + p] = s.x & 0x1FFFF;
        p = atomicAdd(&cur[s.y >> 17], 1); adj[gbase + p] = s.y & 0x1FFFF;
        p = atomicAdd(&cur[s.z >> 17], 1); adj[gbase + p] = s.z & 0x1FFFF;
        p = atomicAdd(&cur[s.w >> 17], 1); adj[gbase + p] = s.w & 0x1FFFF;
    }
    if (i < (count & 3)) {
        int sv = staged[tb + i];
        int p = atomicAdd(&cur[sv >> 17], 1);
        adj[gbase + p] = sv & 0x1FFFF;
    }
}

// ---- MFMA gemm: xs1[n] = (x[n] . W) * dinv[n]; fp16, split A/B layout ----
__global__ void __launch_bounds__(256) gemm_kernel(const float* __restrict__ x,
                                                   const float* __restrict__ w,
                                                   const float* __restrict__ dinv,
                                                   char* __restrict__ xsb, int N) {
    __shared__ bf16x8 shB[3][4][64];
    int t = threadIdx.x;
    for (int idx = t; idx < 3 * 4 * 64; idx += 256) {
        int lane = idx & 63;
        int ks = (idx >> 6) & 3;
        int jt = idx >> 8;
        int j = 16 * jt + (lane & 15);
        int k0 = 32 * ks + 8 * (lane >> 4);
        bf16x8 v;
#pragma unroll
        for (int i = 0; i < 8; ++i)
            v[i] = (j < F_OUT) ? f2bf(w[(k0 + i) * F_OUT + j]) : (short)0;
        shB[jt][ks][lane] = v;
    }
    __syncthreads();
    int wave = t >> 6, lane = t & 63;
    int node0 = blockIdx.x * 64 + wave * 16;
    if (node0 >= N) return;

    const float* xrow = x + (size_t)(node0 + (lane & 15)) * F_IN + 8 * (lane >> 4);
    f32x4 acc0 = {0.f, 0.f, 0.f, 0.f};
    f32x4 acc1 = acc0, acc2 = acc0;
#pragma unroll
    for (int ks = 0; ks < 4; ++ks) {
        float4 lo = *(const float4*)(xrow + 32 * ks);
        float4 hi = *(const float4*)(xrow + 32 * ks + 4);
        bf16x8 a;
        a[0] = f2bf(lo.x); a[1] = f2bf(lo.y); a[2] = f2bf(lo.z); a[3] = f2bf(lo.w);
        a[4] = f2bf(hi.x); a[5] = f2bf(hi.y); a[6] = f2bf(hi.z); a[7] = f2bf(hi.w);
        acc0 = __builtin_amdgcn_mfma_f32_16x16x32_bf16(a, shB[0][ks][lane], acc0, 0, 0, 0);
        acc1 = __builtin_amdgcn_mfma_f32_16x16x32_bf16(a, shB[1][ks][lane], acc1, 0, 0, 0);
        acc2 = __builtin_amdgcn_mfma_f32_16x16x32_bf16(a, shB[2][ks][lane], acc2, 0, 0, 0);
    }
    int colj = lane & 15;
    int rbase = (lane >> 4) * 4;
#pragma unroll
    for (int r = 0; r < 4; ++r) {
        int node = node0 + rbase + r;
        float d = dinv[node];
        _Float16* dstA = (_Float16*)(xsb + (size_t)node * 64);
        dstA[colj]      = (_Float16)(acc0[r] * d);
        dstA[16 + colj] = (_Float16)(acc1[r] * d);
        if (colj < 8)
            ((_Float16*)(xsb + OFFB + (size_t)node * 16))[colj] = (_Float16)(acc2[r] * d);
    }
}

// ---- hop: wave = 4 nodes; lane = (node, sub 0..15). sub<15: edge slot s=sub/5,
// chunk q=sub%5 (q<4 -> A 16B chunk q, q==4 -> B 16B). lane 15: stride-0 dummy.
// 12 edges per wave gather; packed-f16 accumulate; shfl slot-reduce. ----
template <int HOP2>
__global__ void __launch_bounds__(256) hop_kernel(const int* __restrict__ offs,
                                                  const float* __restrict__ dinv,
                                                  const int* __restrict__ adj,
                                                  const char* __restrict__ src,
                                                  char* __restrict__ dst,
                                                  const float* __restrict__ bias,
                                                  float* __restrict__ out) {
    int t = threadIdx.x;
    int wave = t >> 6, lane = t & 63;
    int n0 = blockIdx.x * 16 + wave * 4;
    int node = lane >> 4;
    int sub = lane & 15;
    int n = n0 + node;
    int s = sub / 5;                 // 0..3 (3 only for sub==15)
    int q = sub - s * 5;             // 0..4
    bool padl = (sub == 15);
    unsigned strideB = padl ? 0u : (q == 4 ? 16u : 64u);
    unsigned cstB    = padl ? ADUM : (q == 4 ? OFFB : (unsigned)(q * 16));

    int obase = offs[n];
    int L = offs[n0 + 1] - offs[n0];      // quad-equal, multiple of 3
    int nj = L / 3;

    h2 A0 = {0.f, 0.f}, A1 = A0, A2 = A0, A3 = A0;
#define ACC4(qq) do { A0 += qq.h[0]; A1 += qq.h[1]; A2 += qq.h[2]; A3 += qq.h[3]; } while (0)

    int r = adj[obase + s];
    U4H cur; cur.u = *(const uint4*)(src + (unsigned)r * strideB + cstB);
    for (int j = 1; j < nj; ++j) {
        int r2 = adj[obase + j * 3 + s];
        U4H nxt; nxt.u = *(const uint4*)(src + (unsigned)r2 * strideB + cstB);
        ACC4(cur);
        cur = nxt;
    }
    ACC4(cur);
#undef ACC4

    // reduce across the 3 edge slots: lanes sub, sub+5, sub+10 (mod 15) share q
    int nb = lane & 0x30;
    int i1 = nb | ((sub + 5) % 15);
    int i2 = nb | ((sub + 10) % 15);
    A0 = A0 + shfl_h2(A0, i1) + shfl_h2(A0, i2);
    A1 = A1 + shfl_h2(A1, i1) + shfl_h2(A1, i2);
    A2 = A2 + shfl_h2(A2, i1) + shfl_h2(A2, i2);
    A3 = A3 + shfl_h2(A3, i1) + shfl_h2(A3, i2);

    float f0 = (float)A0[0], f1 = (float)A0[1];
    float f2 = (float)A1[0], f3 = (float)A1[1];
    float f4 = (float)A2[0], f5 = (float)A2[1];
    float f6 = (float)A3[0], f7 = (float)A3[1];

    if (!HOP2) {
        if (sub < 5) {
            float d = dinv[n];
            float dd = d * d;
            uint4 wv;
            wv.x = pack16(f0 * dd, f1 * dd);
            wv.y = pack16(f2 * dd, f3 * dd);
            wv.z = pack16(f4 * dd, f5 * dd);
            wv.w = pack16(f6 * dd, f7 * dd);
            *(uint4*)(dst + (unsigned)n * strideB + cstB) = wv;
        }
    } else {
        float d = dinv[n];
        float4 b0 = ((const float4*)bias)[2 * q];
        float4 b1 = ((const float4*)bias)[2 * q + 1];
        float l0 = f0 * d + b0.x, l1 = f1 * d + b0.y;
        float l2 = f2 * d + b0.z, l3 = f3 * d + b0.w;
        float l4 = f4 * d + b1.x, l5 = f5 * d + b1.y;
        float l6 = f6 * d + b1.z, l7 = f7 * d + b1.w;
        float mp = fmaxf(fmaxf(fmaxf(l0, l1), fmaxf(l2, l3)),
                         fmaxf(fmaxf(l4, l5), fmaxf(l6, l7)));
        float m = mp;
#pragma unroll
        for (int dd = 1; dd <= 4; ++dd)
            m = fmaxf(m, __shfl(mp, nb | ((sub + dd) % 5)));
        const float R = 1.44269504089f;
        float sp = exp2f((l0 - m) * R) + exp2f((l1 - m) * R)
                 + exp2f((l2 - m) * R) + exp2f((l3 - m) * R)
                 + exp2f((l4 - m) * R) + exp2f((l5 - m) * R)
                 + exp2f((l6 - m) * R) + exp2f((l7 - m) * R);
        float sx = sp;
#pragma unroll
        for (int dd = 1; dd <= 4; ++dd)
            sx += __shfl(sp, nb | ((sub + dd) % 5));
        if (sub < 5) {
            float ls = m + 0.69314718056f * log2f(sx);
            float4 q0 = {l0 - ls, l1 - ls, l2 - ls, l3 - ls};
            float4 q1 = {l4 - ls, l5 - ls, l6 - ls, l7 - ls};
            float* op = out + (size_t)n * F_OUT + 8 * q;
            *(float4*)op = q0;
            *(float4*)(op + 4) = q1;
        }
    }
}

extern "C" void kernel_launch(void* const* d_in, const int* in_sizes, int n_in,
                              void* d_out, int out_size, void* d_ws, size_t ws_size,
                              hipStream_t stream) {
    const float* x    = (const float*)d_in[0];
    const int*   eidx = (const int*)d_in[1];
    const float* w    = (const float*)d_in[2];
    const float* bias = (const float*)d_in[3];
    float* out = (float*)d_out;

    const int E = in_sizes[1] / 2;
    const int N = NN;

    char* ws = (char*)d_ws;
    int*   bcursor = (int*)ws;   ws += 4096 * 4;                  // line-padded x16
    int*   offs    = (int*)ws;   ws += (size_t)N * 4;
    float* dinv    = (float*)ws; ws += (size_t)N * 4;
    int*   adj     = (int*)ws;   ws += (size_t)NBUCK * CAP * 4;   // 11.2 MB
    char*  xs1     = ws;         ws += XSBYTES;                   // 8.0 MB (A+B)
    char*  xs2     = ws;         ws += XSBYTES;
    int*   staged  = (int*)ws;                                    // 9.6 MB

    const int* row = eidx;
    const int* col = eidx + E;

    setup_kernel<<<1, 256, 0, stream>>>(bcursor, xs1, xs2);
    part_kernel<<<(E + EPB_C - 1) / EPB_C, 512, 0, stream>>>(row, col, bcursor, staged, E);
    build_kernel<<<NBUCK, 512, 0, stream>>>(staged, bcursor, adj, offs, dinv, N);

    gemm_kernel<<<(N + 63) / 64, 256, 0, stream>>>(x, w, dinv, xs1, N);

    hop_kernel<0><<<N / 16, 256, 0, stream>>>(offs, dinv, adj, xs1, xs2, bias, out);
    hop_kernel<1><<<N / 16, 256, 0, stream>>>(offs, dinv, adj, xs2, nullptr, bias, out);
}

// Round 15
// 117.433 us; speedup vs baseline: 1.1136x; 1.0602x over previous
//
#include <hip/hip_runtime.h>
#include <math.h>

#define NN 100000
#define F_IN 128
#define F_OUT 40
#define BSHIFT 9        // 512 nodes per bucket
#define BSIZE (1 << BSHIFT)
#define NBUCK ((NN + BSIZE - 1) >> BSHIFT)   // 196
#define SCAP 12288      // staged slots per bucket
#define CAP 14336       // padded adj slots per bucket (pad3 + quad-eq)
#define EPB_C 4096      // edges per part block (391 blocks)
// split feature layout: A = cols 0..31 (64 B rows), B = cols 32..39 (16 B rows)
#define OFFB  ((unsigned)((NN + 1) * 64))        // start of B block
#define ADUM  ((unsigned)(NN * 64))              // A dummy row (zeros)
#define XSBYTES ((size_t)8000128)                // (N+1)*80 rounded up

typedef short bf16x8 __attribute__((ext_vector_type(8)));
typedef float f32x4 __attribute__((ext_vector_type(4)));
typedef _Float16 h2 __attribute__((ext_vector_type(2)));

union U4H { uint4 u; h2 h[4]; };

__device__ __forceinline__ short f2bf(float f) {
    union { float f; unsigned u; } uf; uf.f = f;
    unsigned r = uf.u + 0x7FFF + ((uf.u >> 16) & 1);   // RNE
    return (short)(r >> 16);
}

__device__ __forceinline__ unsigned pack16(float x, float y) {
    union { _Float16 h; unsigned short s; } a, b;
    a.h = (_Float16)x; b.h = (_Float16)y;
    return (unsigned)a.s | ((unsigned)b.s << 16);
}

__device__ __forceinline__ h2 shfl_h2(h2 v, int src) {
    int x = __builtin_bit_cast(int, v);
    x = __shfl(x, src);
    return __builtin_bit_cast(h2, x);
}

// ---- partition edges into fixed per-bucket staged regions; packs (c_local<<17)|row.
// bcursor is bucket-RELATIVE (memset 0); block 0 also zeroes the dummy rows. ----
__global__ void __launch_bounds__(512) part_kernel(const int* __restrict__ row,
                                                   const int* __restrict__ col,
                                                   int* __restrict__ bcursor,
                                                   int* __restrict__ staged,
                                                   char* __restrict__ xs1,
                                                   char* __restrict__ xs2, int E) {
    __shared__ int h[NBUCK];
    __shared__ int cur[NBUCK];
    int t = threadIdx.x;
    if (blockIdx.x == 0) {                 // fused dummy-row zeroing
        if (t < 16)      *(unsigned*)(xs1 + ADUM + t * 4) = 0u;
        else if (t < 20) *(unsigned*)(xs1 + OFFB + (size_t)NN * 16 + (t - 16) * 4) = 0u;
        else if (t < 36) *(unsigned*)(xs2 + ADUM + (t - 20) * 4) = 0u;
        else if (t < 40) *(unsigned*)(xs2 + OFFB + (size_t)NN * 16 + (t - 36) * 4) = 0u;
    }
    for (int i = t; i < NBUCK; i += 512) h[i] = 0;
    __syncthreads();
    int e0 = blockIdx.x * EPB_C;
    int ne = min(EPB_C, E - e0);
    int nq = ne >> 2;
    const int4* c4 = (const int4*)(col + e0);
    const int4* r4 = (const int4*)(row + e0);
    for (int k = t; k < nq; k += 512) {
        int4 c = c4[k];
        atomicAdd(&h[c.x >> BSHIFT], 1);
        atomicAdd(&h[c.y >> BSHIFT], 1);
        atomicAdd(&h[c.z >> BSHIFT], 1);
        atomicAdd(&h[c.w >> BSHIFT], 1);
    }
    __syncthreads();
    for (int i = t; i < NBUCK; i += 512)
        cur[i] = (h[i] ? atomicAdd(&bcursor[i * 16], h[i]) : 0) + i * SCAP;
    __syncthreads();
    for (int k = t; k < nq; k += 512) {
        int4 c = c4[k];
        int4 r = r4[k];
        int p;
        p = atomicAdd(&cur[c.x >> BSHIFT], 1); staged[p] = ((c.x & 511) << 17) | r.x;
        p = atomicAdd(&cur[c.y >> BSHIFT], 1); staged[p] = ((c.y & 511) << 17) | r.y;
        p = atomicAdd(&cur[c.z >> BSHIFT], 1); staged[p] = ((c.z & 511) << 17) | r.z;
        p = atomicAdd(&cur[c.w >> BSHIFT], 1); staged[p] = ((c.w & 511) << 17) | r.w;
    }
}

// ---- fused build + gemm. Per bucket: per-node histogram -> offs/dinv/padded adj
// (segment [self, edges..., NN pads], pad3, quad-equalized), then the MFMA gemm
// for this bucket's 512 nodes: xs1[n] = (x[n].W)*dinv[n], fp16 split A/B layout. ----
__global__ void __launch_bounds__(512) build_kernel(const int* __restrict__ staged,
                                                    const int* __restrict__ bcursor,
                                                    int* __restrict__ adj,
                                                    int* __restrict__ offs,
                                                    float* __restrict__ dinv,
                                                    const float* __restrict__ x,
                                                    const float* __restrict__ w,
                                                    char* __restrict__ xsb, int N) {
    __shared__ int hist[BSIZE];
    __shared__ int cur[BSIZE];
    __shared__ int wsum[8];
    __shared__ float sdinv[BSIZE];
    __shared__ bf16x8 shB[3][4][64];       // 12 KB W fragments
    int bk = blockIdx.x;
    int node0 = bk << BSHIFT;
    int sbase = bk * SCAP;
    int count = bcursor[bk * 16];          // relative count
    int gbase = bk * CAP;
    int i = threadIdx.x;
    // stage W fragments (768 entries, 512 threads)
    for (int idx = i; idx < 3 * 4 * 64; idx += 512) {
        int lane = idx & 63;
        int ks = (idx >> 6) & 3;
        int jt = idx >> 8;
        int j = 16 * jt + (lane & 15);
        int k0 = 32 * ks + 8 * (lane >> 4);
        bf16x8 v;
#pragma unroll
        for (int ii = 0; ii < 8; ++ii)
            v[ii] = (j < F_OUT) ? f2bf(w[(k0 + ii) * F_OUT + j]) : (short)0;
        shB[jt][ks][lane] = v;
    }
    hist[i] = 0;
    __syncthreads();
    int nq = count >> 2;
    const int4* st4 = (const int4*)(staged + sbase);
    for (int k = i; k < nq; k += 512) {
        int4 s = st4[k];
        atomicAdd(&hist[s.x >> 17], 1);
        atomicAdd(&hist[s.y >> 17], 1);
        atomicAdd(&hist[s.z >> 17], 1);
        atomicAdd(&hist[s.w >> 17], 1);
    }
    int tb = sbase + (nq << 2);
    if (i < (count & 3)) atomicAdd(&hist[staged[tb + i] >> 17], 1);
    __syncthreads();
    int v = hist[i];
    int Lp = ((v + 3) / 3) * 3;            // pad3(deg+1)
    int L1 = max(Lp, __shfl_xor(Lp, 1));
    int LL = max(L1, __shfl_xor(L1, 2));   // quad-equalized
    int lane = i & 63, wv = i >> 6;
    int xsc = LL;
#pragma unroll
    for (int d = 1; d < 64; d <<= 1) {
        int y = __shfl_up(xsc, d, 64);
        if (lane >= d) xsc += y;
    }
    if (lane == 63) wsum[wv] = xsc;
    __syncthreads();
    int wpre = 0;
    for (int k = 0; k < wv; ++k) wpre += wsum[k];
    int excl = wpre + xsc - LL;
    int n = node0 + i;
    float dv = rsqrtf((float)v + 1.0f);
    sdinv[i] = dv;
    if (n < N) {
        offs[n] = gbase + excl;
        dinv[n] = dv;
        adj[gbase + excl] = n;                        // self edge first
        for (int p = excl + 1 + v; p < excl + LL; ++p)
            adj[gbase + p] = NN;                      // pads -> dummy row
    }
    cur[i] = excl + 1;
    __syncthreads();
    for (int k = i; k < nq; k += 512) {
        int4 s = st4[k];
        int p;
        p = atomicAdd(&cur[s.x >> 17], 1); adj[gbase + p] = s.x & 0x1FFFF;
        p = atomicAdd(&cur[s.y >> 17], 1); adj[gbase + p] = s.y & 0x1FFFF;
        p = atomicAdd(&cur[s.z >> 17], 1); adj[gbase + p] = s.z & 0x1FFFF;
        p = atomicAdd(&cur[s.w >> 17], 1); adj[gbase + p] = s.w & 0x1FFFF;
    }
    if (i < (count & 3)) {
        int sv = staged[tb + i];
        int p = atomicAdd(&cur[sv >> 17], 1);
        adj[gbase + p] = sv & 0x1FFFF;
    }

    // ---- fused gemm: 8 waves x 16 nodes x 4 groups = this bucket's 512 nodes.
    // Depends only on shB + sdinv (synced above) -> overlaps fill across blocks.
    int wave = i >> 6;
    int lane6 = i & 63;
    int colj = lane6 & 15;
    int rbase = (lane6 >> 4) * 4;
#pragma unroll
    for (int g = 0; g < 4; ++g) {
        int node0g = node0 + g * 128 + wave * 16;
        if (node0g >= N) break;            // N%16==0 -> groups all-or-nothing
        const float* xrow = x + (size_t)(node0g + colj) * F_IN + 8 * (lane6 >> 4);
        f32x4 acc0 = {0.f, 0.f, 0.f, 0.f};
        f32x4 acc1 = acc0, acc2 = acc0;
#pragma unroll
        for (int ks = 0; ks < 4; ++ks) {
            float4 lo = *(const float4*)(xrow + 32 * ks);
            float4 hi = *(const float4*)(xrow + 32 * ks + 4);
            bf16x8 a;
            a[0] = f2bf(lo.x); a[1] = f2bf(lo.y); a[2] = f2bf(lo.z); a[3] = f2bf(lo.w);
            a[4] = f2bf(hi.x); a[5] = f2bf(hi.y); a[6] = f2bf(hi.z); a[7] = f2bf(hi.w);
            acc0 = __builtin_amdgcn_mfma_f32_16x16x32_bf16(a, shB[0][ks][lane6], acc0, 0, 0, 0);
            acc1 = __builtin_amdgcn_mfma_f32_16x16x32_bf16(a, shB[1][ks][lane6], acc1, 0, 0, 0);
            acc2 = __builtin_amdgcn_mfma_f32_16x16x32_bf16(a, shB[2][ks][lane6], acc2, 0, 0, 0);
        }
#pragma unroll
        for (int r = 0; r < 4; ++r) {
            int node = node0g + rbase + r;
            float d = sdinv[node - node0];
            _Float16* dstA = (_Float16*)(xsb + (size_t)node * 64);
            dstA[colj]      = (_Float16)(acc0[r] * d);
            dstA[16 + colj] = (_Float16)(acc1[r] * d);
            if (colj < 8)
                ((_Float16*)(xsb + OFFB + (size_t)node * 16))[colj] = (_Float16)(acc2[r] * d);
        }
    }
}

// ---- hop: wave = 4 nodes; lane = (node, sub 0..15). sub<15: edge slot s=sub/5,
// chunk q=sub%5 (q<4 -> A 16B chunk q, q==4 -> B 16B). lane 15: stride-0 dummy.
// 12 edges per wave gather; packed-f16 accumulate; shfl slot-reduce. ----
template <int HOP2>
__global__ void __launch_bounds__(256) hop_kernel(const int* __restrict__ offs,
                                                  const float* __restrict__ dinv,
                                                  const int* __restrict__ adj,
                                                  const char* __restrict__ src,
                                                  char* __restrict__ dst,
                                                  const float* __restrict__ bias,
                                                  float* __restrict__ out) {
    int t = threadIdx.x;
    int wave = t >> 6, lane = t & 63;
    int n0 = blockIdx.x * 16 + wave * 4;
    int node = lane >> 4;
    int sub = lane & 15;
    int n = n0 + node;
    int s = sub / 5;                 // 0..3 (3 only for sub==15)
    int q = sub - s * 5;             // 0..4
    bool padl = (sub == 15);
    unsigned strideB = padl ? 0u : (q == 4 ? 16u : 64u);
    unsigned cstB    = padl ? ADUM : (q == 4 ? OFFB : (unsigned)(q * 16));

    int obase = offs[n];
    int L = offs[n0 + 1] - offs[n0];      // quad-equal, multiple of 3
    int nj = L / 3;

    h2 A0 = {0.f, 0.f}, A1 = A0, A2 = A0, A3 = A0;
#define ACC4(qq) do { A0 += qq.h[0]; A1 += qq.h[1]; A2 += qq.h[2]; A3 += qq.h[3]; } while (0)

    int r = adj[obase + s];
    U4H cur; cur.u = *(const uint4*)(src + (unsigned)r * strideB + cstB);
    for (int j = 1; j < nj; ++j) {
        int r2 = adj[obase + j * 3 + s];
        U4H nxt; nxt.u = *(const uint4*)(src + (unsigned)r2 * strideB + cstB);
        ACC4(cur);
        cur = nxt;
    }
    ACC4(cur);
#undef ACC4

    // reduce across the 3 edge slots: lanes sub, sub+5, sub+10 (mod 15) share q
    int nb = lane & 0x30;
    int i1 = nb | ((sub + 5) % 15);
    int i2 = nb | ((sub + 10) % 15);
    A0 = A0 + shfl_h2(A0, i1) + shfl_h2(A0, i2);
    A1 = A1 + shfl_h2(A1, i1) + shfl_h2(A1, i2);
    A2 = A2 + shfl_h2(A2, i1) + shfl_h2(A2, i2);
    A3 = A3 + shfl_h2(A3, i1) + shfl_h2(A3, i2);

    float f0 = (float)A0[0], f1 = (float)A0[1];
    float f2 = (float)A1[0], f3 = (float)A1[1];
    float f4 = (float)A2[0], f5 = (float)A2[1];
    float f6 = (float)A3[0], f7 = (float)A3[1];

    if (!HOP2) {
        if (sub < 5) {
            float d = dinv[n];
            float dd = d * d;
            uint4 wv;
            wv.x = pack16(f0 * dd, f1 * dd);
            wv.y = pack16(f2 * dd, f3 * dd);
            wv.z = pack16(f4 * dd, f5 * dd);
            wv.w = pack16(f6 * dd, f7 * dd);
            *(uint4*)(dst + (unsigned)n * strideB + cstB) = wv;
        }
    } else {
        float d = dinv[n];
        float4 b0 = ((const float4*)bias)[2 * q];
        float4 b1 = ((const float4*)bias)[2 * q + 1];
        float l0 = f0 * d + b0.x, l1 = f1 * d + b0.y;
        float l2 = f2 * d + b0.z, l3 = f3 * d + b0.w;
        float l4 = f4 * d + b1.x, l5 = f5 * d + b1.y;
        float l6 = f6 * d + b1.z, l7 = f7 * d + b1.w;
        float mp = fmaxf(fmaxf(fmaxf(l0, l1), fmaxf(l2, l3)),
                         fmaxf(fmaxf(l4, l5), fmaxf(l6, l7)));
        float m = mp;
#pragma unroll
        for (int dd = 1; dd <= 4; ++dd)
            m = fmaxf(m, __shfl(mp, nb | ((sub + dd) % 5)));
        const float R = 1.44269504089f;
        float sp = exp2f((l0 - m) * R) + exp2f((l1 - m) * R)
                 + exp2f((l2 - m) * R) + exp2f((l3 - m) * R)
                 + exp2f((l4 - m) * R) + exp2f((l5 - m) * R)
                 + exp2f((l6 - m) * R) + exp2f((l7 - m) * R);
        float sx = sp;
#pragma unroll
        for (int dd = 1; dd <= 4; ++dd)
            sx += __shfl(sp, nb | ((sub + dd) % 5));
        if (sub < 5) {
            float ls = m + 0.69314718056f * log2f(sx);
            float4 q0 = {l0 - ls, l1 - ls, l2 - ls, l3 - ls};
            float4 q1 = {l4 - ls, l5 - ls, l6 - ls, l7 - ls};
            float* op = out + (size_t)n * F_OUT + 8 * q;
            *(float4*)op = q0;
            *(float4*)(op + 4) = q1;
        }
    }
}

extern "C" void kernel_launch(void* const* d_in, const int* in_sizes, int n_in,
                              void* d_out, int out_size, void* d_ws, size_t ws_size,
                              hipStream_t stream) {
    const float* x    = (const float*)d_in[0];
    const int*   eidx = (const int*)d_in[1];
    const float* w    = (const float*)d_in[2];
    const float* bias = (const float*)d_in[3];
    float* out = (float*)d_out;

    const int E = in_sizes[1] / 2;
    const int N = NN;

    char* ws = (char*)d_ws;
    int*   bcursor = (int*)ws;   ws += 4096 * 4;                  // line-padded x16
    int*   offs    = (int*)ws;   ws += (size_t)N * 4;
    float* dinv    = (float*)ws; ws += (size_t)N * 4;
    int*   adj     = (int*)ws;   ws += (size_t)NBUCK * CAP * 4;   // 11.2 MB
    char*  xs1     = ws;         ws += XSBYTES;                   // 8.0 MB (A+B)
    char*  xs2     = ws;         ws += XSBYTES;
    int*   staged  = (int*)ws;                                    // 9.6 MB

    const int* row = eidx;
    const int* col = eidx + E;

    hipMemsetAsync(bcursor, 0, 4096 * 4, stream);
    part_kernel<<<(E + EPB_C - 1) / EPB_C, 512, 0, stream>>>(row, col, bcursor, staged,
                                                             xs1, xs2, E);
    build_kernel<<<NBUCK, 512, 0, stream>>>(staged, bcursor, adj, offs, dinv,
                                            x, w, xs1, N);

    hop_kernel<0><<<N / 16, 256, 0, stream>>>(offs, dinv, adj, xs1, xs2, bias, out);
    hop_kernel<1><<<N / 16, 256, 0, stream>>>(offs, dinv, adj, xs2, nullptr, bias, out);
}